// Round 12
// baseline (129.274 us; speedup 1.0000x reference)
//
#include <hip/hip_runtime.h>
#include <math.h>

#define KC 3
#define S 12
#define SS 1728
#define AB 32
#define TLEN 64
#define NTHREADS 896
#define NWAVES 14
#define NACT 864            // 432 slices x 2 threads
#define LN2F 0.69314718055994530942f

typedef float f32x2 __attribute__((ext_vector_type(2)));

__global__ __launch_bounds__(NTHREADS, 2)   // grid=1 block; don't cap VGPRs at 128
void hmm_fwd_kernel(const int* __restrict__ ys,
                    const float* __restrict__ transition,  // [3][12][12]
                    const float* __restrict__ emission,    // [3][12][32]
                    const float* __restrict__ choice,      // [3]
                    const float* __restrict__ prior,       // [3][12]
                    float* __restrict__ out,
                    float* __restrict__ Tw)                // d_ws: T probs [k][i][16] f32
{
    __shared__ __align__(16) float APL[KC][SS];      // natural order n = 144 s0 + 12 s1 + s2
    __shared__ __align__(16) float BETA[SS];
    __shared__ __align__(16) float ECt[KC][AB][16];  // [k][y][8h+m]
    __shared__ float p_lin[KC][S];
    __shared__ float c_lin[KC];
    __shared__ int   ys_s[TLEN];
    __shared__ float wsum[NWAVES];

    const int tid = threadIdx.x;

    // ---------------- setup: linear-space tables ----------------
    if (tid < TLEN) ys_s[tid] = ys[tid];

    if (tid == 0) {
        float m = fmaxf(fmaxf(choice[0], choice[1]), choice[2]);
        float e0 = __expf(choice[0]-m), e1 = __expf(choice[1]-m), e2 = __expf(choice[2]-m);
        float inv = 1.f / (e0+e1+e2);
        c_lin[0] = e0*inv; c_lin[1] = e1*inv; c_lin[2] = e2*inv;
    }
    if (tid >= 1 && tid < 1 + KC) {
        int k = tid - 1;
        float m = -INFINITY;
        #pragma unroll
        for (int i = 0; i < S; ++i) m = fmaxf(m, prior[k*S + i]);
        float ev[S]; float s = 0.f;
        #pragma unroll
        for (int i = 0; i < S; ++i) { ev[i] = __expf(prior[k*S + i] - m); s += ev[i]; }
        float inv = 1.f / s;
        #pragma unroll
        for (int i = 0; i < S; ++i) p_lin[k][i] = ev[i] * inv;
    }
    if (tid >= 64 && tid < 64 + KC*S) {
        // transition rows -> softmax probs into GLOBAL d_ws
        // row (k,i) at Tw[(k*12+i)*16]; cols j<6 -> slot j, j>=6 -> slot j+2
        int r = tid - 64;
        int k = r / S, i = r % S;
        const float* row = transition + (k*S + i)*S;
        float m = -INFINITY;
        #pragma unroll
        for (int j = 0; j < S; ++j) m = fmaxf(m, row[j]);
        float ev[S]; float s = 0.f;
        #pragma unroll
        for (int j = 0; j < S; ++j) { ev[j] = __expf(row[j] - m); s += ev[j]; }
        float inv = 1.f / s;
        float* tg = Tw + (k*S + i)*16;
        #pragma unroll
        for (int j = 0; j < S; ++j) tg[(j < 6) ? j : j + 2] = ev[j] * inv;
    }
    if (tid >= 128 && tid < 128 + KC*S) {    // emission -> ECt = C[k]*softmax
        int r = tid - 128;
        int k = r / S, sj = r % S;
        float cm = fmaxf(fmaxf(choice[0], choice[1]), choice[2]);
        float ce = __expf(choice[k]-cm) /
                   (__expf(choice[0]-cm) + __expf(choice[1]-cm) + __expf(choice[2]-cm));
        const float* row = emission + (k*S + sj)*AB;
        float m = -INFINITY;
        #pragma unroll
        for (int a = 0; a < AB; ++a) m = fmaxf(m, row[a]);
        float ev[AB]; float s = 0.f;
        #pragma unroll
        for (int a = 0; a < AB; ++a) { ev[a] = __expf(row[a] - m); s += ev[a]; }
        float inv = ce / s;
        const int slot = (sj / 6) * 8 + (sj % 6);
        #pragma unroll
        for (int a = 0; a < AB; ++a) ECt[k][a][slot] = ev[a] * inv;
    }
    __syncthreads();   // drains vmcnt -> Tw visible

    // ---------------- per-thread statics ----------------
    const bool act = tid < NACT;
    const int ct = act ? tid : (NACT - 1);
    const int sl = ct >> 1;            // slice 0..431
    const int h  = ct & 1;             // output half: columns 6h..6h+5
    const int sk = sl / 144;           // chain
    const int q  = sl % 144;
    const int qh = q / 12, ql = q % 12;

    const int rdb = (sk == 0) ? q : (sk == 1) ? 144*qh + ql : 12*q;
    const int wstr = (sk == 0) ? 144 : (sk == 1) ? 12 : 1;
    const int wbas = rdb + wstr * 6 * h;
    float* const wap = &APL[sk][wbas];
    const float* const ecp = &ECt[sk][0][8*h];

    // T columns 6h..6h+5 from global, as 3 packed-f32 pairs per row
    const float* const tgb = Tw + (sk*S)*16 + 8*h;
    f32x2 TP0[S], TP1[S], TP2[S];
    #pragma unroll
    for (int i = 0; i < S; ++i) {
        float4 t03 = *reinterpret_cast<const float4*>(&tgb[16*i]);
        float2 t45 = *reinterpret_cast<const float2*>(&tgb[16*i + 4]);
        TP0[i] = (f32x2){t03.x, t03.y};
        TP1[i] = (f32x2){t03.z, t03.w};
        TP2[i] = (f32x2){t45.x, t45.y};
    }

    // init A planes: thread owns natural states 2p, 2p+1
    if (act) {
        const int sA = 2*tid;
        const int a0 = sA/144, b0 = (sA/12)%12, c0 = sA%12;
        const float pp = p_lin[0][a0]*p_lin[1][b0];
        const float pA = pp*p_lin[2][c0], pB = pp*p_lin[2][c0+1];
        #pragma unroll
        for (int k = 0; k < KC; ++k) {
            float2 v; v.x = pA*c_lin[k]; v.y = pB*c_lin[k];
            *reinterpret_cast<float2*>(&APL[k][sA]) = v;
        }
    }
    __syncthreads();

    float logR = 0.f, invR = 1.f;
    const int s2p = 2*tid;

// One scan step. RED is a literal 0/1 (t%8==7 steps do the renorm reduce).
#define STEP(TT, RED) { \
    const int y_ = ys_s[(TT)]; \
    float4 e03; float2 e45; \
    if (act) { \
        /* E prefetch: depends only on y_, completes under barrier-A slack */ \
        e03 = *reinterpret_cast<const float4*>(&ecp[y_*16]); \
        e45 = *reinterpret_cast<const float2*>(&ecp[y_*16 + 4]); \
        float2 a0 = *reinterpret_cast<const float2*>(&APL[0][s2p]); \
        float2 a1 = *reinterpret_cast<const float2*>(&APL[1][s2p]); \
        float2 a2 = *reinterpret_cast<const float2*>(&APL[2][s2p]); \
        float2 b; \
        b.x = (a0.x + a1.x + a2.x) * invR; \
        b.y = (a0.y + a1.y + a2.y) * invR; \
        *reinterpret_cast<float2*>(&BETA[s2p]) = b; \
    } \
    __syncthreads();   /* barrier A: BETA ready */ \
    float o0=0.f,o1=0.f,o2=0.f,o3=0.f,o4=0.f,o5=0.f; \
    if (act) { \
        float bv0,bv1,bv2,bv3,bv4,bv5,bv6,bv7,bv8,bv9,bv10,bv11; \
        if (sk == 0) { \
            bv0=BETA[rdb+0*144]; bv1=BETA[rdb+1*144]; bv2 =BETA[rdb+2*144];  bv3 =BETA[rdb+3*144]; \
            bv4=BETA[rdb+4*144]; bv5=BETA[rdb+5*144]; bv6 =BETA[rdb+6*144];  bv7 =BETA[rdb+7*144]; \
            bv8=BETA[rdb+8*144]; bv9=BETA[rdb+9*144]; bv10=BETA[rdb+10*144]; bv11=BETA[rdb+11*144]; \
        } else if (sk == 1) { \
            bv0=BETA[rdb+0*12]; bv1=BETA[rdb+1*12]; bv2 =BETA[rdb+2*12];  bv3 =BETA[rdb+3*12]; \
            bv4=BETA[rdb+4*12]; bv5=BETA[rdb+5*12]; bv6 =BETA[rdb+6*12];  bv7 =BETA[rdb+7*12]; \
            bv8=BETA[rdb+8*12]; bv9=BETA[rdb+9*12]; bv10=BETA[rdb+10*12]; bv11=BETA[rdb+11*12]; \
        } else { \
            float4 r0 = *reinterpret_cast<const float4*>(&BETA[rdb + 0]); \
            float4 r1 = *reinterpret_cast<const float4*>(&BETA[rdb + 4]); \
            float4 r2 = *reinterpret_cast<const float4*>(&BETA[rdb + 8]); \
            bv0=r0.x; bv1=r0.y; bv2 =r0.z; bv3 =r0.w; \
            bv4=r1.x; bv5=r1.y; bv6 =r1.z; bv7 =r1.w; \
            bv8=r2.x; bv9=r2.y; bv10=r2.z; bv11=r2.w; \
        } \
        f32x2 ac0 = {0.f,0.f}, ac1 = {0.f,0.f}, ac2 = {0.f,0.f}; \
        { \
            f32x2 bb; \
            bb = (f32x2){bv0,bv0};   ac0=__builtin_elementwise_fma(bb,TP0[0],ac0);  ac1=__builtin_elementwise_fma(bb,TP1[0],ac1);  ac2=__builtin_elementwise_fma(bb,TP2[0],ac2); \
            bb = (f32x2){bv1,bv1};   ac0=__builtin_elementwise_fma(bb,TP0[1],ac0);  ac1=__builtin_elementwise_fma(bb,TP1[1],ac1);  ac2=__builtin_elementwise_fma(bb,TP2[1],ac2); \
            bb = (f32x2){bv2,bv2};   ac0=__builtin_elementwise_fma(bb,TP0[2],ac0);  ac1=__builtin_elementwise_fma(bb,TP1[2],ac1);  ac2=__builtin_elementwise_fma(bb,TP2[2],ac2); \
            bb = (f32x2){bv3,bv3};   ac0=__builtin_elementwise_fma(bb,TP0[3],ac0);  ac1=__builtin_elementwise_fma(bb,TP1[3],ac1);  ac2=__builtin_elementwise_fma(bb,TP2[3],ac2); \
            bb = (f32x2){bv4,bv4};   ac0=__builtin_elementwise_fma(bb,TP0[4],ac0);  ac1=__builtin_elementwise_fma(bb,TP1[4],ac1);  ac2=__builtin_elementwise_fma(bb,TP2[4],ac2); \
            bb = (f32x2){bv5,bv5};   ac0=__builtin_elementwise_fma(bb,TP0[5],ac0);  ac1=__builtin_elementwise_fma(bb,TP1[5],ac1);  ac2=__builtin_elementwise_fma(bb,TP2[5],ac2); \
            bb = (f32x2){bv6,bv6};   ac0=__builtin_elementwise_fma(bb,TP0[6],ac0);  ac1=__builtin_elementwise_fma(bb,TP1[6],ac1);  ac2=__builtin_elementwise_fma(bb,TP2[6],ac2); \
            bb = (f32x2){bv7,bv7};   ac0=__builtin_elementwise_fma(bb,TP0[7],ac0);  ac1=__builtin_elementwise_fma(bb,TP1[7],ac1);  ac2=__builtin_elementwise_fma(bb,TP2[7],ac2); \
            bb = (f32x2){bv8,bv8};   ac0=__builtin_elementwise_fma(bb,TP0[8],ac0);  ac1=__builtin_elementwise_fma(bb,TP1[8],ac1);  ac2=__builtin_elementwise_fma(bb,TP2[8],ac2); \
            bb = (f32x2){bv9,bv9};   ac0=__builtin_elementwise_fma(bb,TP0[9],ac0);  ac1=__builtin_elementwise_fma(bb,TP1[9],ac1);  ac2=__builtin_elementwise_fma(bb,TP2[9],ac2); \
            bb = (f32x2){bv10,bv10}; ac0=__builtin_elementwise_fma(bb,TP0[10],ac0); ac1=__builtin_elementwise_fma(bb,TP1[10],ac1); ac2=__builtin_elementwise_fma(bb,TP2[10],ac2); \
            bb = (f32x2){bv11,bv11}; ac0=__builtin_elementwise_fma(bb,TP0[11],ac0); ac1=__builtin_elementwise_fma(bb,TP1[11],ac1); ac2=__builtin_elementwise_fma(bb,TP2[11],ac2); \
        } \
        o0 = ac0.x*e03.x; o1 = ac0.y*e03.y; o2 = ac1.x*e03.z; \
        o3 = ac1.y*e03.w; o4 = ac2.x*e45.x; o5 = ac2.y*e45.y; \
        if (sk == 2) { \
            if (h == 0) { \
                *reinterpret_cast<float4*>(&wap[0]) = make_float4(o0, o1, o2, o3); \
                *reinterpret_cast<float2*>(&wap[4]) = make_float2(o4, o5); \
            } else { \
                *reinterpret_cast<float2*>(&wap[0]) = make_float2(o0, o1); \
                *reinterpret_cast<float4*>(&wap[2]) = make_float4(o2, o3, o4, o5); \
            } \
        } else { \
            wap[0*wstr] = o0; wap[1*wstr] = o1; wap[2*wstr] = o2; \
            wap[3*wstr] = o3; wap[4*wstr] = o4; wap[5*wstr] = o5; \
        } \
    } \
    if (RED) { \
        float part = o0 + o1 + o2 + o3 + o4 + o5; \
        part += __shfl_xor(part, 32); part += __shfl_xor(part, 16); \
        part += __shfl_xor(part, 8);  part += __shfl_xor(part, 4); \
        part += __shfl_xor(part, 2);  part += __shfl_xor(part, 1); \
        if ((tid & 63) == 0) wsum[tid >> 6] = part; \
    } \
    __syncthreads();   /* barrier B */ \
    if (RED) { \
        float R_ = 0.f; \
        _Pragma("unroll") \
        for (int w = 0; w < NWAVES; ++w) R_ += wsum[w]; \
        if ((TT) != TLEN-1) { invR = __builtin_amdgcn_rcpf(R_); logR += __log2f(R_); } \
        else invR = 1.f; \
    } else { \
        invR = 1.f; \
    } }

    #pragma unroll 1
    for (int tb = 0; tb < TLEN; tb += 8) {
        STEP(tb + 0, 0)
        STEP(tb + 1, 0)
        STEP(tb + 2, 0)
        STEP(tb + 3, 0)
        STEP(tb + 4, 0)
        STEP(tb + 5, 0)
        STEP(tb + 6, 0)
        STEP(tb + 7, 1)
    }

    // final: total mass at t=63 is in wsum (its normalizer never applied)
    if (tid == 0) {
        float R = 0.f;
        #pragma unroll
        for (int w = 0; w < NWAVES; ++w) R += wsum[w];
        out[0] = LN2F * (__log2f(R) + logR);
    }
}

extern "C" void kernel_launch(void* const* d_in, const int* in_sizes, int n_in,
                              void* d_out, int out_size, void* d_ws, size_t ws_size,
                              hipStream_t stream) {
    const int*   ys         = (const int*)  d_in[0];
    const float* transition = (const float*)d_in[1];
    const float* emission   = (const float*)d_in[2];
    const float* choice     = (const float*)d_in[3];
    const float* prior      = (const float*)d_in[4];
    float* out = (float*)d_out;
    float* Tw  = (float*)d_ws;   // 3*12*16 floats = 2304 B

    hipLaunchKernelGGL(hmm_fwd_kernel, dim3(1), dim3(NTHREADS), 0, stream,
                       ys, transition, emission, choice, prior, out, Tw);
}